// Round 2
// baseline (903.906 us; speedup 1.0000x reference)
//
#include <hip/hip_runtime.h>
#include <math.h>

// TopKGating: logits = x @ W^T + b  -> softmax(8) -> top-2 (indices, values)
// x: [131072, 1024] f32, W: [8, 1024] f32, b: [8] f32
// out: [N*2] indices (as float) then [N*2] values, flat concat.
//
// Memory-bound on streaming x (537 MB, > L3). Design: wave-private LDS
// staging (NO __syncthreads in the K-loop -- barriers force vmcnt(0) drains
// that kill the prefetch pipeline) + register double-pump so chunk c+1's
// global loads are in flight while chunk c is computed from LDS.

#define NUM_TOKENS 131072
#define DIM        1024          // floats per token
#define D4         (DIM / 4)     // 256 float4 per token
#define NE         8
#define TPB        256           // 4 waves per block
#define TOKW       64            // tokens per wave (1 per lane)
#define DC         64            // floats staged per chunk
#define DC4        (DC / 4)      // 16 float4
#define NCHUNK     (DIM / DC)    // 16
#define RS4        17            // LDS row stride in float4 (68 floats; even bank spread)

__global__ __launch_bounds__(TPB, 2)
void topk_gating_kernel(const float* __restrict__ x,
                        const float* __restrict__ W,
                        const float* __restrict__ b,
                        float* __restrict__ out)
{
    // 4 waves x 64 rows x 17 float4 x 16B = 69632 B -> 2 blocks/CU
    __shared__ float4 lds4[4 * TOKW * RS4];

    const int t    = threadIdx.x;
    const int wave = t >> 6;
    const int lane = t & 63;
    const int wtok0 = blockIdx.x * TPB + wave * TOKW;  // this wave's first token
    float4* wb4 = lds4 + wave * TOKW * RS4;            // wave-private region

    const float4* x4 = (const float4*)x;  // [N, 256]
    const float4* W4 = (const float4*)W;  // [8, 256]

    const int h  = lane >> 4;   // 0..3  : row sub-index within a staging instr
    const int lo = lane & 15;   // 0..15 : float4 column within chunk

    float acc[NE];
#pragma unroll
    for (int e = 0; e < NE; ++e) acc[e] = 0.f;

    // ---- software pipeline: pf holds the next chunk's tile (16 float4/lane) ----
    float4 pf[16];
#pragma unroll
    for (int q = 0; q < 16; ++q) {
        int r = q * 4 + h;  // token row within wave tile
        pf[q] = x4[(size_t)(wtok0 + r) * D4 + lo];  // chunk 0
    }

    for (int c = 0; c < NCHUNK; ++c) {
        // Drain pf (loads landed during previous chunk's compute) into LDS.
        // Wave-private: no barrier needed, compiler vmcnt/lgkmcnt handle deps.
#pragma unroll
        for (int q = 0; q < 16; ++q) {
            int r = q * 4 + h;
            wb4[r * RS4 + lo] = pf[q];
        }
        // Issue next chunk's global loads NOW; they fly during compute below.
        if (c + 1 < NCHUNK) {
#pragma unroll
            for (int q = 0; q < 16; ++q) {
                int r = q * 4 + h;
                pf[q] = x4[(size_t)(wtok0 + r) * D4 + (c + 1) * DC4 + lo];
            }
        }
        // Compute: each lane reads its own token's row; W index is wave-uniform
        // (loop counters only) -> scalar s_load path, constant-cache backed.
#pragma unroll
        for (int j = 0; j < DC4; ++j) {
            float4 xv = wb4[lane * RS4 + j];
#pragma unroll
            for (int e = 0; e < NE; ++e) {
                float4 w = W4[e * D4 + c * DC4 + j];
                acc[e] = fmaf(xv.x, w.x, acc[e]);
                acc[e] = fmaf(xv.y, w.y, acc[e]);
                acc[e] = fmaf(xv.z, w.z, acc[e]);
                acc[e] = fmaf(xv.w, w.w, acc[e]);
            }
        }
    }

    // ---- epilogue: bias, stable top-2 (ties -> lower index, matches lax.top_k) ----
    float logit[NE];
#pragma unroll
    for (int e = 0; e < NE; ++e) logit[e] = acc[e] + b[e];

    float v1 = -INFINITY, v2 = -INFINITY;
    int   i1 = 0,         i2 = 0;
#pragma unroll
    for (int e = 0; e < NE; ++e) {
        float v = logit[e];
        if (v > v1)      { v2 = v1; i2 = i1; v1 = v; i1 = e; }
        else if (v > v2) { v2 = v;  i2 = e; }
    }

    float sum = 0.f;
#pragma unroll
    for (int e = 0; e < NE; ++e) sum += __expf(logit[e] - v1);
    float inv = 1.0f / sum;
    float p1  = inv;                    // exp(v1 - v1) * inv
    float p2  = __expf(v2 - v1) * inv;

    int n = wtok0 + lane;
    float2* outi = (float2*)out;                            // indices (as float)
    float2* outv = (float2*)(out + 2 * (size_t)NUM_TOKENS); // values
    outi[n] = make_float2((float)i1, (float)i2);
    outv[n] = make_float2(p1, p2);
}

extern "C" void kernel_launch(void* const* d_in, const int* in_sizes, int n_in,
                              void* d_out, int out_size, void* d_ws, size_t ws_size,
                              hipStream_t stream) {
    const float* x = (const float*)d_in[0];
    const float* W = (const float*)d_in[1];
    const float* b = (const float*)d_in[2];
    float* out = (float*)d_out;

    dim3 grid(NUM_TOKENS / TPB);  // 512 blocks, 2 blocks/CU
    dim3 block(TPB);
    topk_gating_kernel<<<grid, block, 0, stream>>>(x, W, b, out);
}